// Round 11
// baseline (148.490 us; speedup 1.0000x reference)
//
#include <hip/hip_runtime.h>
#include <hip/hip_bf16.h>
#include <stdint.h>

#define BATCH 4
#define SEQ 1024
#define DMODEL 1024
#define NH 16
#define HD 64

typedef __attribute__((ext_vector_type(8))) short short8;
typedef __attribute__((ext_vector_type(4))) float f32x4;
typedef __attribute__((ext_vector_type(4))) unsigned short ushort4v;

__device__ __forceinline__ unsigned short f2bf(float f) {
    union { float f; uint32_t u; } v; v.f = f;
    uint32_t r = v.u + 0x7fff + ((v.u >> 16) & 1);   // RNE
    return (unsigned short)(r >> 16);
}

__device__ __forceinline__ uint32_t pack2bf(float lo, float hi) {
    union { __hip_bfloat162 h; uint32_t u; } cv;
    cv.h = __float22bfloat162_rn(make_float2(lo, hi));   // v_cvt_pk_bf16_f32 (RNE)
    return cv.u;
}

// ---------------- kernel 1: prep = transpose W -> Wt bf16 (x-cast fused into GEMM) ------
__global__ __launch_bounds__(256) void prep_kernel(const float* __restrict__ W,
                                                   unsigned short* __restrict__ Wt) {
    __shared__ float tile[32][33];
    int r = blockIdx.x;                 // 0..3071
    int nb = (r % 96) * 32;
    int kb = (r / 96) * 32;
    int tx = threadIdx.x & 31;
    int ty = threadIdx.x >> 5;
#pragma unroll
    for (int i = 0; i < 4; i++) {
        int k = kb + ty + i * 8;
        tile[ty + i * 8][tx] = W[(size_t)k * 3072 + nb + tx];
    }
    __syncthreads();
#pragma unroll
    for (int i = 0; i < 4; i++) {
        int n = nb + ty + i * 8;
        Wt[(size_t)n * 1024 + kb + tx] = f2bf(tile[tx][ty + i * 8]);
    }
}

// ---------------- kernel 3: QKV GEMM (bf16 MFMA, reg-prefetch, fused x-cast) ------------
// A staged straight from fp32 x (float4 pairs -> cvt_pk_bf16 during LDS write).
// Flat grid 768 with 8m x 12n per-XCD patches (id%8 = XCD).
#define BM 128
#define BN 128
#define BKK 64
#define QSCALE 0.18033688011112042f   // 0.125 * log2(e)

__global__ __launch_bounds__(256, 3) void qkv_gemm_kernel(
    const float* __restrict__ x,             // [4096][1024] fp32
    const unsigned short* __restrict__ wt,   // [3072][1024] bf16
    const float* __restrict__ bias,          // [3072]
    unsigned short* __restrict__ Qb,
    unsigned short* __restrict__ Kb,
    unsigned short* __restrict__ VbT)        // [bh][d][s]
{
    __shared__ __align__(16) unsigned short As[BM][64];
    __shared__ __align__(16) unsigned short Bs[BN][64];
    int tid = threadIdx.x;
    int wave = tid >> 6, lane = tid & 63;
    int quad = lane >> 4, l16 = lane & 15;
    int wm = wave >> 1, wn = wave & 1;

    int id = blockIdx.x;
    int xc = id & 7, rr_ = id >> 3;           // rr_: 0..95
    int m_t = (xc & 3) * 8 + (rr_ & 7);
    int n_t = (xc >> 2) * 12 + (rr_ >> 3);
    int m0 = m_t * BM;
    int n0 = n_t * BN;

    int grow = lane >> 3;
    int gcol = ((lane & 7) ^ grow) << 3;
    const float* gA = x + (size_t)(m0 + wave * 32 + grow) * 1024 + gcol;
    const unsigned short* gB = wt + (size_t)(n0 + wave * 32 + grow) * 1024 + gcol;
    unsigned short* ldsA = &As[wave * 32][0] + lane * 8;
    unsigned short* ldsB = &Bs[wave * 32][0] + lane * 8;
    int sw = l16 & 7;

    float4 areg[4][2];
    short8 breg[4];
#pragma unroll
    for (int i = 0; i < 4; i++) {
        areg[i][0] = *(const float4*)(gA + (size_t)i * 8 * 1024);
        areg[i][1] = *(const float4*)(gA + (size_t)i * 8 * 1024 + 4);
        breg[i] = *(const short8*)(gB + (size_t)i * 8 * 1024);
    }

    f32x4 acc[4][4] = {};
    for (int k0 = 0; k0 < 1024; k0 += BKK) {
        __syncthreads();
#pragma unroll
        for (int i = 0; i < 4; i++) {
            union { uint32_t w[4]; short8 s; } pk;
            pk.w[0] = pack2bf(areg[i][0].x, areg[i][0].y);
            pk.w[1] = pack2bf(areg[i][0].z, areg[i][0].w);
            pk.w[2] = pack2bf(areg[i][1].x, areg[i][1].y);
            pk.w[3] = pack2bf(areg[i][1].z, areg[i][1].w);
            *(short8*)(ldsA + i * 512) = pk.s;
            *(short8*)(ldsB + i * 512) = breg[i];
        }
        __syncthreads();
        if (k0 + BKK < 1024) {
#pragma unroll
            for (int i = 0; i < 4; i++) {
                areg[i][0] = *(const float4*)(gA + (size_t)i * 8 * 1024 + k0 + BKK);
                areg[i][1] = *(const float4*)(gA + (size_t)i * 8 * 1024 + k0 + BKK + 4);
                breg[i] = *(const short8*)(gB + (size_t)i * 8 * 1024 + k0 + BKK);
            }
        }
#pragma unroll
        for (int kk = 0; kk < BKK; kk += 32) {
            int kb = kk >> 3;
            short8 af[4], bf[4];
#pragma unroll
            for (int t = 0; t < 4; t++) {
                int ar = wm * 64 + t * 16 + l16;
                af[t] = *(const short8*)&As[ar][((kb + quad) ^ sw) << 3];
            }
#pragma unroll
            for (int t = 0; t < 4; t++) {
                int br = wn * 64 + t * 16 + l16;
                bf[t] = *(const short8*)&Bs[br][((kb + quad) ^ sw) << 3];
            }
#pragma unroll
            for (int mt = 0; mt < 4; mt++)
#pragma unroll
                for (int nt = 0; nt < 4; nt++)
                    acc[mt][nt] = __builtin_amdgcn_mfma_f32_16x16x32_bf16(
                        af[mt], bf[nt], acc[mt][nt], 0, 0, 0);
        }
    }
#pragma unroll
    for (int nt = 0; nt < 4; nt++) {
        int n = n0 + wn * 64 + nt * 16 + l16;
        int h = n / 192;
        int c = n - h * 192;
        int which = c >> 6;
        int d = c & 63;
        float bv = bias[n];
        if (which == 2) {
#pragma unroll
            for (int mt = 0; mt < 4; mt++) {
                int m = m0 + wm * 64 + mt * 16 + quad * 4;
                int b = m >> 10, s = m & 1023;
                ushort4v o;
                o[0] = f2bf(acc[mt][nt][0] + bv);
                o[1] = f2bf(acc[mt][nt][1] + bv);
                o[2] = f2bf(acc[mt][nt][2] + bv);
                o[3] = f2bf(acc[mt][nt][3] + bv);
                *(ushort4v*)&VbT[((size_t)((b * 16 + h) * 64 + d)) * 1024 + s] = o;
            }
        } else {
            unsigned short* dst = (which == 0) ? Qb : Kb;
            float sc = (which == 0) ? QSCALE : 1.0f;
#pragma unroll
            for (int mt = 0; mt < 4; mt++) {
#pragma unroll
                for (int r2 = 0; r2 < 4; r2++) {
                    int m = m0 + wm * 64 + mt * 16 + quad * 4 + r2;
                    int b = m >> 10, s = m & 1023;
                    dst[((size_t)((b * 16 + h) * 1024 + s)) * 64 + d] = f2bf((acc[mt][nt][r2] + bv) * sc);
                }
            }
        }
    }
}

// ---------------- kernel 4: flash attention, hybrid q/k wave-split + LDS double-buffer --
// BQ=128, BKV=128, grid 512. Wave (qh, kh) owns q-half x key-half. Double-buffered K/V
// LDS (2 x 32 KB): ONE barrier per tile; prefetch of tile t+1 (issued before the barrier)
// overlaps the whole compute of tile t. Last tile computes from buf1 -> reduction can
// safely reuse buf0 as scratch.
#define BQ 128
#define BKV 128

__global__ __launch_bounds__(256, 2) void attn_kernel(
    const unsigned short* __restrict__ Qb,
    const unsigned short* __restrict__ Kb,
    const unsigned short* __restrict__ VbT,
    float* __restrict__ out)
{
    __shared__ __align__(16) char smem[65536];   // 2 x (Ks 16K | Vts 16K)
    __shared__ float lbuf[4][4][16];
    float* red = (float*)smem;                   // aliases buf0 (dead after last tile)

    int tid = threadIdx.x;
    int wave = tid >> 6, lane = tid & 63;
    int quad = lane >> 4, l16 = lane & 15;
    int qh = wave & 1, kh = wave >> 1;

    int id = blockIdx.x;
    int xcd = id & 7, rest = id >> 3;
    int qt = rest & 7, grp = rest >> 3;
    int bh = grp * 8 + xcd;
    int q0 = qt * BQ;

    const unsigned short* Qp = Qb + (size_t)bh * SEQ * HD;
    const unsigned short* Kp = Kb + (size_t)bh * SEQ * HD;
    const unsigned short* Vp = VbT + (size_t)bh * HD * SEQ;   // [d][s]

    int f_k = (l16 & 3) | (((l16 >> 2) & 1) << 2);
    int f_v = l16 & 7;
    int prow = (kh << 6) + ((l16 >> 2) << 3) + (l16 & 3);

    // Q fragments hoisted: q = q0 + qh*64 + g*16 + l16
    short8 qf[4][2];
#pragma unroll
    for (int g = 0; g < 4; g++)
#pragma unroll
        for (int kc = 0; kc < 2; kc++)
            qf[g][kc] = *(const short8*)&Qp[(size_t)(q0 + qh * 64 + g * 16 + l16) * HD + kc * 32 + quad * 8];

    // K/V register prefetch
    short8 kreg[4], vreg[4];
    auto load_tile = [&](int kt) {
#pragma unroll
        for (int i = 0; i < 4; i++) {
            int idx = i * 256 + tid;
            int krow = idx >> 3, kpb = idx & 7;
            int klb = kpb ^ ((krow & 3) | (((krow >> 3) & 1) << 2));
            kreg[i] = *(const short8*)&Kp[(size_t)(kt + krow) * HD + klb * 8];
            int vrow = idx >> 4, vpb = idx & 15;
            int vlb = vpb ^ (vrow & 7);
            vreg[i] = *(const short8*)&Vp[(size_t)vrow * SEQ + kt + vlb * 8];
        }
    };
    load_tile(0);

    f32x4 oacc[4][4] = {};
    float lsum[4] = {0.f, 0.f, 0.f, 0.f};

    for (int t = 0; t < SEQ / BKV; t++) {
        int p = t & 1;
        unsigned short (*Ks)[64]   = (unsigned short(*)[64])(smem + p * 32768);
        unsigned short (*Vts)[128] = (unsigned short(*)[128])(smem + p * 32768 + 16384);
        // regs -> LDS buf p (tile t's data; no one reads buf p until the barrier below)
#pragma unroll
        for (int i = 0; i < 4; i++) {
            int idx = i * 256 + tid;
            int krow = idx >> 3, kpb = idx & 7;
            *(short8*)&Ks[krow][kpb * 8] = kreg[i];
            int vrow = idx >> 4, vpb = idx & 15;
            *(short8*)&Vts[vrow][vpb * 8] = vreg[i];
        }
        if (t + 1 < SEQ / BKV) load_tile((t + 1) * BKV);   // latency spans barrier+compute
        __syncthreads();

#pragma unroll
        for (int c = 0; c < 2; c++) {
            int base = prow + (c << 5);
            short8 kf0[2], kf1[2];
#pragma unroll
            for (int kc = 0; kc < 2; kc++) {
                kf0[kc] = *(const short8*)&Ks[base][(((kc << 2) + quad) ^ f_k) * 8];
                kf1[kc] = *(const short8*)&Ks[base + 4][(((kc << 2) + quad) ^ f_k) * 8];
            }
            short8 vf[4];
#pragma unroll
            for (int nt = 0; nt < 4; nt++)
                vf[nt] = *(const short8*)&Vts[nt * 16 + l16][(((kh << 3) + (c << 2) + quad) ^ f_v) * 8];
#pragma unroll
            for (int g = 0; g < 4; g++) {
                f32x4 s0 = {}, s1 = {};
#pragma unroll
                for (int kc = 0; kc < 2; kc++) {
                    s0 = __builtin_amdgcn_mfma_f32_16x16x32_bf16(kf0[kc], qf[g][kc], s0, 0, 0, 0);
                    s1 = __builtin_amdgcn_mfma_f32_16x16x32_bf16(kf1[kc], qf[g][kc], s1, 0, 0, 0);
                }
                float p0 = __builtin_amdgcn_exp2f(s0[0]);
                float p1 = __builtin_amdgcn_exp2f(s0[1]);
                float p2 = __builtin_amdgcn_exp2f(s0[2]);
                float p3 = __builtin_amdgcn_exp2f(s0[3]);
                float p4 = __builtin_amdgcn_exp2f(s1[0]);
                float p5 = __builtin_amdgcn_exp2f(s1[1]);
                float p6 = __builtin_amdgcn_exp2f(s1[2]);
                float p7 = __builtin_amdgcn_exp2f(s1[3]);
                lsum[g] += ((p0 + p1) + (p2 + p3)) + ((p4 + p5) + (p6 + p7));
                union { uint32_t w[4]; short8 s; } pf;
                pf.w[0] = pack2bf(p0, p1);
                pf.w[1] = pack2bf(p2, p3);
                pf.w[2] = pack2bf(p4, p5);
                pf.w[3] = pack2bf(p6, p7);
#pragma unroll
                for (int nt = 0; nt < 4; nt++)
                    oacc[g][nt] = __builtin_amdgcn_mfma_f32_16x16x32_bf16(vf[nt], pf.s, oacc[g][nt], 0, 0, 0);
            }
        }
    }

    // ---- cross-wave reduction (kh pairs share q-half); red aliases buf0 (safe: last
    // tile used buf1, and buf0's last readers drained at the final barrier) ----
#pragma unroll
    for (int g = 0; g < 4; g++) {
        lsum[g] += __shfl_xor(lsum[g], 16, 64);
        lsum[g] += __shfl_xor(lsum[g], 32, 64);
    }
    int off = quad * 16 + l16;
    __syncthreads();
    if (kh == 1) {
        float* rp = red + qh * 4096;
#pragma unroll
        for (int g = 0; g < 4; g++)
#pragma unroll
            for (int nt = 0; nt < 4; nt++)
#pragma unroll
                for (int rr = 0; rr < 4; rr++)
                    rp[((g * 4 + nt) * 4 + rr) * 64 + off] = oacc[g][nt][rr];
        if (quad == 0)
#pragma unroll
            for (int g = 0; g < 4; g++) lbuf[wave][g][l16] = lsum[g];
    }
    __syncthreads();
    if (kh == 0) {
        float* rp = red + qh * 4096;
        int b = bh >> 4, h = bh & 15;
#pragma unroll
        for (int g = 0; g < 4; g++) {
            float l = lsum[g] + lbuf[wave + 2][g][l16];
            float inv = 1.f / l;
            int s = q0 + qh * 64 + g * 16 + l16;
#pragma unroll
            for (int nt = 0; nt < 4; nt++) {
                float4 o;
                o.x = (oacc[g][nt][0] + rp[((g * 4 + nt) * 4 + 0) * 64 + off]) * inv;
                o.y = (oacc[g][nt][1] + rp[((g * 4 + nt) * 4 + 1) * 64 + off]) * inv;
                o.z = (oacc[g][nt][2] + rp[((g * 4 + nt) * 4 + 2) * 64 + off]) * inv;
                o.w = (oacc[g][nt][3] + rp[((g * 4 + nt) * 4 + 3) * 64 + off]) * inv;
                *(float4*)&out[(size_t)(b * SEQ + s) * DMODEL + h * HD + nt * 16 + quad * 4] = o;
            }
        }
    }
}

// ---------------- launch ----------------
extern "C" void kernel_launch(void* const* d_in, const int* in_sizes, int n_in,
                              void* d_out, int out_size, void* d_ws, size_t ws_size,
                              hipStream_t stream) {
    const float* x    = (const float*)d_in[0];
    const float* W    = (const float*)d_in[1];
    const float* bias = (const float*)d_in[2];
    float* out = (float*)d_out;
    char* ws = (char*)d_ws;

    unsigned short* wt  = (unsigned short*)(ws + 8388608);
    unsigned short* Qb  = (unsigned short*)(ws + 14680064);
    unsigned short* Kb  = (unsigned short*)(ws + 23068672);
    unsigned short* VbT = (unsigned short*)(ws + 31457280);

    prep_kernel<<<3072, 256, 0, stream>>>(W, wt);
    qkv_gemm_kernel<<<768, 256, 0, stream>>>(x, wt, bias, Qb, Kb, VbT);
    attn_kernel<<<512, 256, 0, stream>>>(Qb, Kb, VbT, out);
}

// Round 12
// 144.563 us; speedup vs baseline: 1.0272x; 1.0272x over previous
//
#include <hip/hip_runtime.h>
#include <hip/hip_bf16.h>
#include <stdint.h>

#define BATCH 4
#define SEQ 1024
#define DMODEL 1024
#define NH 16
#define HD 64

typedef __attribute__((ext_vector_type(8))) short short8;
typedef __attribute__((ext_vector_type(4))) float f32x4;
typedef __attribute__((ext_vector_type(4))) unsigned short ushort4v;

__device__ __forceinline__ unsigned short f2bf(float f) {
    union { float f; uint32_t u; } v; v.f = f;
    uint32_t r = v.u + 0x7fff + ((v.u >> 16) & 1);   // RNE
    return (unsigned short)(r >> 16);
}

__device__ __forceinline__ uint32_t pack2bf(float lo, float hi) {
    union { __hip_bfloat162 h; uint32_t u; } cv;
    cv.h = __float22bfloat162_rn(make_float2(lo, hi));   // v_cvt_pk_bf16_f32 (RNE)
    return cv.u;
}

// ---------------- kernel 1: fused prep (cast x -> bf16; transpose W -> Wt bf16) ---------
__global__ __launch_bounds__(256) void prep_kernel(const float* __restrict__ x,
                                                   const float* __restrict__ W,
                                                   unsigned short* __restrict__ xb,
                                                   unsigned short* __restrict__ Wt) {
    __shared__ float tile[32][33];
    int bid = blockIdx.x;
    if (bid < 2048) {
        int t = bid * 256 + threadIdx.x;
        const float4* p = (const float4*)x + (size_t)t * 2;
        float4 a = p[0], b = p[1];
        short8 o;
        o[0] = (short)f2bf(a.x); o[1] = (short)f2bf(a.y);
        o[2] = (short)f2bf(a.z); o[3] = (short)f2bf(a.w);
        o[4] = (short)f2bf(b.x); o[5] = (short)f2bf(b.y);
        o[6] = (short)f2bf(b.z); o[7] = (short)f2bf(b.w);
        *((short8*)xb + t) = o;
    } else {
        int r = bid - 2048;
        int nb = (r % 96) * 32;
        int kb = (r / 96) * 32;
        int tx = threadIdx.x & 31;
        int ty = threadIdx.x >> 5;
#pragma unroll
        for (int i = 0; i < 4; i++) {
            int k = kb + ty + i * 8;
            tile[ty + i * 8][tx] = W[(size_t)k * 3072 + nb + tx];
        }
        __syncthreads();
#pragma unroll
        for (int i = 0; i < 4; i++) {
            int n = nb + ty + i * 8;
            Wt[(size_t)n * 1024 + kb + tx] = f2bf(tile[tx][ty + i * 8]);
        }
    }
}

// ---------------- kernel 3: QKV GEMM (r10 version: bf16 inputs, reg-prefetch) -----------
#define BM 128
#define BN 128
#define BKK 64
#define QSCALE 0.18033688011112042f   // 0.125 * log2(e)

__global__ __launch_bounds__(256, 3) void qkv_gemm_kernel(
    const unsigned short* __restrict__ xb,   // [4096][1024]
    const unsigned short* __restrict__ wt,   // [3072][1024]
    const float* __restrict__ bias,          // [3072]
    unsigned short* __restrict__ Qb,
    unsigned short* __restrict__ Kb,
    unsigned short* __restrict__ VbT)        // [bh][d][s]
{
    __shared__ __align__(16) unsigned short As[BM][64];
    __shared__ __align__(16) unsigned short Bs[BN][64];
    int tid = threadIdx.x;
    int wave = tid >> 6, lane = tid & 63;
    int quad = lane >> 4, l16 = lane & 15;
    int wm = wave >> 1, wn = wave & 1;

    int id = blockIdx.x;
    int xc = id & 7, rr_ = id >> 3;           // rr_: 0..95
    int m_t = (xc & 3) * 8 + (rr_ & 7);
    int n_t = (xc >> 2) * 12 + (rr_ >> 3);
    int m0 = m_t * BM;
    int n0 = n_t * BN;

    int grow = lane >> 3;
    int gcol = ((lane & 7) ^ grow) << 3;
    const unsigned short* gA = xb + (size_t)(m0 + wave * 32 + grow) * 1024 + gcol;
    const unsigned short* gB = wt + (size_t)(n0 + wave * 32 + grow) * 1024 + gcol;
    unsigned short* ldsA = &As[wave * 32][0] + lane * 8;
    unsigned short* ldsB = &Bs[wave * 32][0] + lane * 8;
    int sw = l16 & 7;

    short8 areg[4], breg[4];
#pragma unroll
    for (int i = 0; i < 4; i++) {
        areg[i] = *(const short8*)(gA + (size_t)i * 8 * 1024);
        breg[i] = *(const short8*)(gB + (size_t)i * 8 * 1024);
    }

    f32x4 acc[4][4] = {};
    for (int k0 = 0; k0 < 1024; k0 += BKK) {
        __syncthreads();
#pragma unroll
        for (int i = 0; i < 4; i++) {
            *(short8*)(ldsA + i * 512) = areg[i];
            *(short8*)(ldsB + i * 512) = breg[i];
        }
        __syncthreads();
        if (k0 + BKK < 1024) {
#pragma unroll
            for (int i = 0; i < 4; i++) {
                areg[i] = *(const short8*)(gA + (size_t)i * 8 * 1024 + k0 + BKK);
                breg[i] = *(const short8*)(gB + (size_t)i * 8 * 1024 + k0 + BKK);
            }
        }
#pragma unroll
        for (int kk = 0; kk < BKK; kk += 32) {
            int kb = kk >> 3;
            short8 af[4], bf[4];
#pragma unroll
            for (int t = 0; t < 4; t++) {
                int ar = wm * 64 + t * 16 + l16;
                af[t] = *(const short8*)&As[ar][((kb + quad) ^ sw) << 3];
            }
#pragma unroll
            for (int t = 0; t < 4; t++) {
                int br = wn * 64 + t * 16 + l16;
                bf[t] = *(const short8*)&Bs[br][((kb + quad) ^ sw) << 3];
            }
#pragma unroll
            for (int mt = 0; mt < 4; mt++)
#pragma unroll
                for (int nt = 0; nt < 4; nt++)
                    acc[mt][nt] = __builtin_amdgcn_mfma_f32_16x16x32_bf16(
                        af[mt], bf[nt], acc[mt][nt], 0, 0, 0);
        }
    }
#pragma unroll
    for (int nt = 0; nt < 4; nt++) {
        int n = n0 + wn * 64 + nt * 16 + l16;
        int h = n / 192;
        int c = n - h * 192;
        int which = c >> 6;
        int d = c & 63;
        float bv = bias[n];
        if (which == 2) {
#pragma unroll
            for (int mt = 0; mt < 4; mt++) {
                int m = m0 + wm * 64 + mt * 16 + quad * 4;
                int b = m >> 10, s = m & 1023;
                ushort4v o;
                o[0] = f2bf(acc[mt][nt][0] + bv);
                o[1] = f2bf(acc[mt][nt][1] + bv);
                o[2] = f2bf(acc[mt][nt][2] + bv);
                o[3] = f2bf(acc[mt][nt][3] + bv);
                *(ushort4v*)&VbT[((size_t)((b * 16 + h) * 64 + d)) * 1024 + s] = o;
            }
        } else {
            unsigned short* dst = (which == 0) ? Qb : Kb;
            float sc = (which == 0) ? QSCALE : 1.0f;
#pragma unroll
            for (int mt = 0; mt < 4; mt++) {
#pragma unroll
                for (int r2 = 0; r2 < 4; r2++) {
                    int m = m0 + wm * 64 + mt * 16 + quad * 4 + r2;
                    int b = m >> 10, s = m & 1023;
                    dst[((size_t)((b * 16 + h) * 1024 + s)) * 64 + d] = f2bf((acc[mt][nt][r2] + bv) * sc);
                }
            }
        }
    }
}

// ---------------- kernel 4: flash attention, BARRIER-FREE main loop ---------------------
// Same math/permutation as the verified r10 kernel, but the LDS round-trip is removed:
// every K/V fragment is a direct 16B contiguous global load (L1-resident per tile:
// K+V = 32 KB; wave pairs load identical fragments -> L1 hits). Zero __syncthreads in
// the main loop -> no vmcnt(0) barrier drain; kf double-buffered one tile ahead.
// Key map (wave kh, chunk c, subtile t_): key = kt + kh*64 + c*32 + (l16>>2)*8 + t_*4 + (l16&3)
// V map: vf[nt] = VbT[d = nt*16+l16][kt + kh*64 + c*32 + quad*8 .. +7]
#define BQ 128
#define BKV 128

__global__ __launch_bounds__(256, 2) void attn_kernel(
    const unsigned short* __restrict__ Qb,
    const unsigned short* __restrict__ Kb,
    const unsigned short* __restrict__ VbT,
    float* __restrict__ out)
{
    __shared__ float red[8192];          // 32 KB, epilogue only
    __shared__ float lbuf[4][4][16];

    int tid = threadIdx.x;
    int wave = tid >> 6, lane = tid & 63;
    int quad = lane >> 4, l16 = lane & 15;
    int qh = wave & 1, kh = wave >> 1;

    int id = blockIdx.x;
    int xcd = id & 7, rest = id >> 3;
    int qt = rest & 7, grp = rest >> 3;
    int bh = grp * 8 + xcd;
    int q0 = qt * BQ;

    const unsigned short* Qp = Qb + (size_t)bh * SEQ * HD;
    const unsigned short* Kp = Kb + (size_t)bh * SEQ * HD;
    const unsigned short* Vp = VbT + (size_t)bh * HD * SEQ;   // [d][s]

    // hoisted Q fragments: q = q0 + qh*64 + g*16 + l16, d = kc*32 + quad*8
    short8 qf[4][2];
#pragma unroll
    for (int g = 0; g < 4; g++)
#pragma unroll
        for (int kc = 0; kc < 2; kc++)
            qf[g][kc] = *(const short8*)&Qp[(size_t)(q0 + qh * 64 + g * 16 + l16) * HD + kc * 32 + quad * 8];

    const unsigned short* kbase = Kp + (size_t)(kh * 64 + ((l16 >> 2) << 3) + (l16 & 3)) * HD + quad * 8;
    const unsigned short* vbase = Vp + (size_t)l16 * SEQ + kh * 64 + quad * 8;

    f32x4 oacc[4][4] = {};
    float lsum[4] = {0.f, 0.f, 0.f, 0.f};

    short8 kf[2][2][2][2];   // [buf][c][t_][kc]
#pragma unroll
    for (int c = 0; c < 2; c++)
#pragma unroll
        for (int t_ = 0; t_ < 2; t_++)
#pragma unroll
            for (int kc = 0; kc < 2; kc++)
                kf[0][c][t_][kc] = *(const short8*)(kbase + (size_t)(c * 32 + t_ * 4) * HD + kc * 32);

#pragma unroll
    for (int t = 0; t < SEQ / BKV; t++) {
        int kt = t * BKV;
        int cur = t & 1, nxt = cur ^ 1;
        if (t + 1 < SEQ / BKV) {            // next tile's K flies under this tile's compute
#pragma unroll
            for (int c = 0; c < 2; c++)
#pragma unroll
                for (int t_ = 0; t_ < 2; t_++)
#pragma unroll
                    for (int kc = 0; kc < 2; kc++)
                        kf[nxt][c][t_][kc] = *(const short8*)(kbase + (size_t)(kt + BKV + c * 32 + t_ * 4) * HD + kc * 32);
        }
#pragma unroll
        for (int c = 0; c < 2; c++) {
            short8 vf[4];
#pragma unroll
            for (int nt = 0; nt < 4; nt++)
                vf[nt] = *(const short8*)(vbase + (size_t)nt * 16 * SEQ + kt + c * 32);
#pragma unroll
            for (int g = 0; g < 4; g++) {
                f32x4 s0 = {}, s1 = {};
#pragma unroll
                for (int kc = 0; kc < 2; kc++) {
                    s0 = __builtin_amdgcn_mfma_f32_16x16x32_bf16(kf[cur][c][0][kc], qf[g][kc], s0, 0, 0, 0);
                    s1 = __builtin_amdgcn_mfma_f32_16x16x32_bf16(kf[cur][c][1][kc], qf[g][kc], s1, 0, 0, 0);
                }
                float p0 = __builtin_amdgcn_exp2f(s0[0]);
                float p1 = __builtin_amdgcn_exp2f(s0[1]);
                float p2 = __builtin_amdgcn_exp2f(s0[2]);
                float p3 = __builtin_amdgcn_exp2f(s0[3]);
                float p4 = __builtin_amdgcn_exp2f(s1[0]);
                float p5 = __builtin_amdgcn_exp2f(s1[1]);
                float p6 = __builtin_amdgcn_exp2f(s1[2]);
                float p7 = __builtin_amdgcn_exp2f(s1[3]);
                lsum[g] += ((p0 + p1) + (p2 + p3)) + ((p4 + p5) + (p6 + p7));
                union { uint32_t w[4]; short8 s; } pf;
                pf.w[0] = pack2bf(p0, p1);
                pf.w[1] = pack2bf(p2, p3);
                pf.w[2] = pack2bf(p4, p5);
                pf.w[3] = pack2bf(p6, p7);
#pragma unroll
                for (int nt = 0; nt < 4; nt++)
                    oacc[g][nt] = __builtin_amdgcn_mfma_f32_16x16x32_bf16(vf[nt], pf.s, oacc[g][nt], 0, 0, 0);
            }
        }
    }

    // ---- cross-wave reduction (kh pairs share q-half) ----
#pragma unroll
    for (int g = 0; g < 4; g++) {            // quads summed disjoint key subsets
        lsum[g] += __shfl_xor(lsum[g], 16, 64);
        lsum[g] += __shfl_xor(lsum[g], 32, 64);
    }
    int off = quad * 16 + l16;
    if (kh == 1) {
        float* rp = red + qh * 4096;
#pragma unroll
        for (int g = 0; g < 4; g++)
#pragma unroll
            for (int nt = 0; nt < 4; nt++)
#pragma unroll
                for (int rr = 0; rr < 4; rr++)
                    rp[((g * 4 + nt) * 4 + rr) * 64 + off] = oacc[g][nt][rr];
        if (quad == 0)
#pragma unroll
            for (int g = 0; g < 4; g++) lbuf[wave][g][l16] = lsum[g];
    }
    __syncthreads();
    if (kh == 0) {
        float* rp = red + qh * 4096;
        int b = bh >> 4, h = bh & 15;
#pragma unroll
        for (int g = 0; g < 4; g++) {
            float l = lsum[g] + lbuf[wave + 2][g][l16];
            float inv = 1.f / l;
            int s = q0 + qh * 64 + g * 16 + l16;
#pragma unroll
            for (int nt = 0; nt < 4; nt++) {
                float4 o;
                o.x = (oacc[g][nt][0] + rp[((g * 4 + nt) * 4 + 0) * 64 + off]) * inv;
                o.y = (oacc[g][nt][1] + rp[((g * 4 + nt) * 4 + 1) * 64 + off]) * inv;
                o.z = (oacc[g][nt][2] + rp[((g * 4 + nt) * 4 + 2) * 64 + off]) * inv;
                o.w = (oacc[g][nt][3] + rp[((g * 4 + nt) * 4 + 3) * 64 + off]) * inv;
                *(float4*)&out[(size_t)(b * SEQ + s) * DMODEL + h * HD + nt * 16 + quad * 4] = o;
            }
        }
    }
}

// ---------------- launch ----------------
extern "C" void kernel_launch(void* const* d_in, const int* in_sizes, int n_in,
                              void* d_out, int out_size, void* d_ws, size_t ws_size,
                              hipStream_t stream) {
    const float* x    = (const float*)d_in[0];
    const float* W    = (const float*)d_in[1];
    const float* bias = (const float*)d_in[2];
    float* out = (float*)d_out;
    char* ws = (char*)d_ws;

    unsigned short* xb  = (unsigned short*)(ws);
    unsigned short* wt  = (unsigned short*)(ws + 8388608);
    unsigned short* Qb  = (unsigned short*)(ws + 14680064);
    unsigned short* Kb  = (unsigned short*)(ws + 23068672);
    unsigned short* VbT = (unsigned short*)(ws + 31457280);

    prep_kernel<<<5120, 256, 0, stream>>>(x, W, xb, wt);
    qkv_gemm_kernel<<<768, 256, 0, stream>>>(xb, wt, bias, Qb, Kb, VbT);
    attn_kernel<<<512, 256, 0, stream>>>(Qb, Kb, VbT, out);
}